// Round 3
// baseline (408.960 us; speedup 1.0000x reference)
//
#include <hip/hip_runtime.h>
#include <math.h>

// Problem constants (fixed by the reference):
#define NEXP 4               // n
#define STREAM 4096          // N*C
#define NOUT 24              // n*n + 2n
#define NTOK 16384           // B*L
#define SK_ITERS 20

// Tiling:
#define T_PER_BLOCK 8        // tokens per block (phi reuse factor)
#define CHUNK 512            // k-values staged per chunk
#define NCHUNK (STREAM / CHUNK)   // 8

// ---------------------------------------------------------------------------
// Kernel A: phiT[j][k] = scale[k] * phi[k][j]   (24 x 4096, transposed+scaled)
// ---------------------------------------------------------------------------
__global__ __launch_bounds__(256) void k_transpose_scale(
    const float* __restrict__ phi, const float* __restrict__ scale,
    float* __restrict__ phiT) {
  int flat = blockIdx.x * 256 + threadIdx.x;   // 0..98303, flat = k*24 + j
  int k = flat / NOUT;
  int j = flat - k * NOUT;
  phiT[j * STREAM + k] = phi[flat] * scale[k];
}

// ---------------------------------------------------------------------------
// Fused kernel: matvec body identical to the verified k_matvec (single-buffer,
// two barriers per chunk), epilogue writes m to LDS and runs the verified
// k_heads body as a tail on the first 128 threads (16 lanes per token).
// ---------------------------------------------------------------------------
__global__ __launch_bounds__(256) void k_fused(
    const float* __restrict__ x, const float* __restrict__ phiT,
    const float* __restrict__ bias,
    const float* __restrict__ a_pre_p, const float* __restrict__ a_post_p,
    const float* __restrict__ a_res_p, float* __restrict__ out) {
  __shared__ float lds_x[T_PER_BLOCK * CHUNK];   // 16 KB
  __shared__ float lds_inv[T_PER_BLOCK];         // 1/rms per token
  __shared__ float lds_m[T_PER_BLOCK * NOUT];    // 192 floats

  const int tid  = threadIdx.x;
  const int w    = tid >> 6;
  const int lane = tid & 63;
  const int tok0 = blockIdx.x * T_PER_BLOCK;

  const float4* x4    = (const float4*)x;
  const float4* phiT4 = (const float4*)phiT;
  float4*       lds4  = (float4*)lds_x;

  float acc[T_PER_BLOCK][6];
#pragma unroll
  for (int t = 0; t < T_PER_BLOCK; t++)
#pragma unroll
    for (int jj = 0; jj < 6; jj++) acc[t][jj] = 0.0f;
  float ssq0 = 0.0f, ssq1 = 0.0f;

  for (int ch = 0; ch < NCHUNK; ch++) {
    // ---- stage: wave w loads tokens 2w and 2w+1 (128 float4 each) ----
#pragma unroll
    for (int tl = 0; tl < 2; tl++) {
      int t = 2 * w + tl;
      int tok = tok0 + t;
#pragma unroll
      for (int i = 0; i < 2; i++) {
        int pos4 = i * 64 + lane;
        float4 v = x4[tok * (STREAM / 4) + ch * (CHUNK / 4) + pos4];
        lds4[t * (CHUNK / 4) + pos4] = v;
        float s = v.x * v.x + v.y * v.y + v.z * v.z + v.w * v.w;
        if (tl == 0) ssq0 += s; else ssq1 += s;
      }
    }
    __syncthreads();
    // ---- compute: 6 phi columns (j = 6w+jj) x 8 tokens ----
#pragma unroll
    for (int i = 0; i < 2; i++) {
      int k4 = i * 64 + lane;
      float4 p[6];
#pragma unroll
      for (int jj = 0; jj < 6; jj++)
        p[jj] = phiT4[(6 * w + jj) * (STREAM / 4) + ch * (CHUNK / 4) + k4];
#pragma unroll
      for (int t = 0; t < T_PER_BLOCK; t++) {
        float4 xv = lds4[t * (CHUNK / 4) + k4];
#pragma unroll
        for (int jj = 0; jj < 6; jj++) {
          float a = acc[t][jj];
          a = fmaf(xv.x, p[jj].x, a);
          a = fmaf(xv.y, p[jj].y, a);
          a = fmaf(xv.z, p[jj].z, a);
          a = fmaf(xv.w, p[jj].w, a);
          acc[t][jj] = a;
        }
      }
    }
    __syncthreads();
  }

  // ---- wave-reduce sumsq (tokens 2w, 2w+1) ----
#pragma unroll
  for (int d = 1; d < 64; d <<= 1) {
    ssq0 += __shfl_xor(ssq0, d, 64);
    ssq1 += __shfl_xor(ssq1, d, 64);
  }
  if (lane == 0) {
    lds_inv[2 * w]     = 1.0f / sqrtf(ssq0 * (1.0f / STREAM) + 1e-20f);
    lds_inv[2 * w + 1] = 1.0f / sqrtf(ssq1 * (1.0f / STREAM) + 1e-20f);
  }

  // ---- wave-reduce the 48 accumulators (butterfly; all lanes get totals) ----
#pragma unroll
  for (int d = 1; d < 64; d <<= 1) {
#pragma unroll
    for (int t = 0; t < T_PER_BLOCK; t++)
#pragma unroll
      for (int jj = 0; jj < 6; jj++)
        acc[t][jj] += __shfl_xor(acc[t][jj], d, 64);
  }
  __syncthreads();   // lds_inv visible to all waves

  // ---- write m into LDS: lane t*6+jj stores token t, column j=6w+jj ----
#pragma unroll
  for (int t = 0; t < T_PER_BLOCK; t++) {
    float inv = lds_inv[t];
#pragma unroll
    for (int jj = 0; jj < 6; jj++) {
      if (lane == t * 6 + jj) {
        int j = 6 * w + jj;
        lds_m[t * NOUT + j] = acc[t][jj] * inv + bias[j];
      }
    }
  }
  __syncthreads();   // lds_m visible

  // ---- heads + Sinkhorn tail: 16 lanes per token, first 2 waves only ----
  if (tid < T_PER_BLOCK * 16) {
    int t = tid >> 4;
    int e = tid & 15;            // r*4 + c
    int tok = tok0 + t;

    float a_res = *a_res_p;
    float M = expf(a_res * lds_m[t * NOUT + 2 * NEXP + e]);
#pragma unroll 1
    for (int it = 0; it < SK_ITERS; it++) {
      float rs = M + __shfl_xor(M, 1, 64);
      rs += __shfl_xor(rs, 2, 64);
      M = M / (rs + 1e-12f);
      float cs = M + __shfl_xor(M, 4, 64);
      cs += __shfl_xor(cs, 8, 64);
      M = M / (cs + 1e-12f);
    }
    out[2 * NTOK * NEXP + tok * 16 + e] = M;   // h_res at offset 131072

    if (e < NEXP) {
      float z = (*a_pre_p) * lds_m[t * NOUT + e];
      out[tok * NEXP + e] = 1.0f / (1.0f + expf(-z));
    } else if (e < 2 * NEXP) {
      int j = e - NEXP;
      float z = (*a_post_p) * lds_m[t * NOUT + NEXP + j];
      out[NTOK * NEXP + tok * NEXP + j] = 2.0f / (1.0f + expf(-z));
    }
  }
}

// ---------------------------------------------------------------------------
extern "C" void kernel_launch(void* const* d_in, const int* in_sizes, int n_in,
                              void* d_out, int out_size, void* d_ws, size_t ws_size,
                              hipStream_t stream) {
  const float* x      = (const float*)d_in[0];
  const float* scale  = (const float*)d_in[1];
  const float* phi    = (const float*)d_in[2];
  const float* bias   = (const float*)d_in[3];
  const float* a_pre  = (const float*)d_in[4];
  const float* a_post = (const float*)d_in[5];
  const float* a_res  = (const float*)d_in[6];
  float* out = (float*)d_out;

  float* phiT = (float*)d_ws;   // 24*4096 = 98304 floats

  k_transpose_scale<<<(NOUT * STREAM) / 256, 256, 0, stream>>>(phi, scale, phiT);
  k_fused<<<NTOK / T_PER_BLOCK, 256, 0, stream>>>(x, phiT, bias, a_pre, a_post,
                                                  a_res, out);
}